// Round 6
// baseline (326.950 us; speedup 1.0000x reference)
//
#include <hip/hip_runtime.h>

// Problem constants
#define NBANDS 64
#define LATENT 256
#define HIDDEN 512
#define GQ 8
#define KQ 1024
#define GD 32
#define NROWS 16000   // B*T = 16*1000

// d_out float offsets
#define OUT_BH   0
#define OUT_ZE   1024000
#define OUT_ZQ   5120000
#define OUT_IDX  9216000
#define OUT_LOSS 9344000

// ws float offsets.  H region [0,8192000) is live ONLY between enc1 and enc2;
// bf16 buffers overlay it and MUST be written after enc2.
#define WS_H     0
#define WS_H2BF_F  0
#define WS_ZQB_F   4096000
#define WS_W1B_F   6144000
#define WS_W2B_F   6209536
// Swizzled VQ records (written by prep_wT, staged to LDS by vq_mfma):
// per (g,chunk of 64 codes): {h[256],m[256],l[256]} slots of 8 shorts in LANE
// order (slot = nt*64 + quad*16 + l16) + cn[64] f32 = 6272 shorts = 12544 B.
// 128 records = 401408 floats, inside dead-H overlay region.
#define WS_REC_F   6240000
#define VQ_REC_SH  6272
#define WS_CN    8192000
#define WS_LOSS  8200192

typedef __attribute__((ext_vector_type(8))) short bf16x8;
typedef __attribute__((ext_vector_type(4))) float f32x4;

__device__ __forceinline__ unsigned short f2bf(float f) {
  unsigned u = __builtin_bit_cast(unsigned, f);
  unsigned r = u + 0x7FFFu + ((u >> 16) & 1u);   // RNE; inputs finite
  return (unsigned short)(r >> 16);
}

__device__ __forceinline__ float bf2f(unsigned short h) {
  return __builtin_bit_cast(float, ((unsigned)h) << 16);
}

// 3-way bf16 split: x ~= h + m + l with residual ~2^-24 |x|.
__device__ __forceinline__ void split3(float x, unsigned short& h,
                                       unsigned short& m, unsigned short& l) {
  h = f2bf(x);
  const float r1 = x - bf2f(h);
  m = f2bf(r1);
  const float r2 = r1 - bf2f(m);
  l = f2bf(r2);
}

// ---------------------------------------------------------------------------
// fp32 GEMM, 128xBN tile, TMxTN microtile, templated BK, 256 threads.
// Ascending-k accumulation regardless of BK -> bit-identical results.
// ---------------------------------------------------------------------------
template<int BN, int TM, int TN, int BK, bool RELU>
__global__ __launch_bounds__(256) void gemm_f32(
    const float* __restrict__ A, const float* __restrict__ B,
    const float* __restrict__ bias, float* __restrict__ C,
    int M, int N, int K) {
  constexpr int BM = 128;
  constexpr int NTX = BN / TN;
  constexpr int AF4 = BK / 8;
  constexpr int QPR = BN / 4;
  constexpr int BF4 = BK * BN / 1024;

  __shared__ float As[BK][BM + 8];
  __shared__ float Bs[BK][BN + 4];

  const int tid = threadIdx.x;
  const int tx = tid % NTX;
  const int ty = tid / NTX;
  const int row0 = blockIdx.y * BM;
  const int col0 = blockIdx.x * BN;

  const int arow = tid >> 1;
  const int akq  = (tid & 1) * (BK / 2);

  float acc[TM][TN] = {};

  for (int k0 = 0; k0 < K; k0 += BK) {
    float4 av[AF4], bv[BF4];
#pragma unroll
    for (int q = 0; q < AF4; ++q)
      av[q] = *reinterpret_cast<const float4*>(
          &A[(size_t)(row0 + arow) * K + k0 + akq + q * 4]);
#pragma unroll
    for (int t = 0; t < BF4; ++t) {
      const int qq = tid * BF4 + t;
      const int bk = qq / QPR, bn4 = qq % QPR;
      bv[t] = *reinterpret_cast<const float4*>(
          &B[(size_t)(k0 + bk) * N + col0 + bn4 * 4]);
    }
    __syncthreads();
#pragma unroll
    for (int q = 0; q < AF4; ++q) {
      As[akq + q * 4 + 0][arow] = av[q].x;
      As[akq + q * 4 + 1][arow] = av[q].y;
      As[akq + q * 4 + 2][arow] = av[q].z;
      As[akq + q * 4 + 3][arow] = av[q].w;
    }
#pragma unroll
    for (int t = 0; t < BF4; ++t) {
      const int qq = tid * BF4 + t;
      const int bk = qq / QPR, bn4 = qq % QPR;
      *reinterpret_cast<float4*>(&Bs[bk][bn4 * 4]) = bv[t];
    }
    __syncthreads();

#pragma unroll
    for (int kk = 0; kk < BK; ++kk) {
      float a[TM], b[TN];
#pragma unroll
      for (int q = 0; q < TM / 4; ++q) {
        float4 v = *reinterpret_cast<const float4*>(&As[kk][ty * TM + q * 4]);
        a[q * 4 + 0] = v.x; a[q * 4 + 1] = v.y;
        a[q * 4 + 2] = v.z; a[q * 4 + 3] = v.w;
      }
#pragma unroll
      for (int q = 0; q < TN / 4; ++q) {
        float4 v = *reinterpret_cast<const float4*>(&Bs[kk][tx * TN + q * 4]);
        b[q * 4 + 0] = v.x; b[q * 4 + 1] = v.y;
        b[q * 4 + 2] = v.z; b[q * 4 + 3] = v.w;
      }
#pragma unroll
      for (int i = 0; i < TM; ++i)
#pragma unroll
        for (int j = 0; j < TN; ++j)
          acc[i][j] = fmaf(a[i], b[j], acc[i][j]);
    }
  }

  float bb[TN];
#pragma unroll
  for (int q = 0; q < TN / 4; ++q) {
    float4 v = *reinterpret_cast<const float4*>(&bias[col0 + tx * TN + q * 4]);
    bb[q * 4 + 0] = v.x; bb[q * 4 + 1] = v.y;
    bb[q * 4 + 2] = v.z; bb[q * 4 + 3] = v.w;
  }
#pragma unroll
  for (int i = 0; i < TM; ++i) {
    const int r = row0 + ty * TM + i;
#pragma unroll
    for (int q = 0; q < TN / 4; ++q) {
      float4 v;
      float* vp = &v.x;
#pragma unroll
      for (int j = 0; j < 4; ++j) {
        float t = acc[i][q * 4 + j] + bb[q * 4 + j];
        if (RELU) t = fmaxf(t, 0.0f);
        vp[j] = t;
      }
      *reinterpret_cast<float4*>(&C[(size_t)r * N + col0 + tx * TN + q * 4]) = v;
    }
  }
}

// ---------------------------------------------------------------------------
// bf16 MFMA GEMM with TRANSPOSED B (BT[n][k]) -> b128 B-staging.
// DO_LOSS: block(0,0) tid0 finalizes the vq loss scalar.
// ---------------------------------------------------------------------------
template<int WM, bool OUT_BF16, bool DO_LOSS>
__global__ __launch_bounds__(256) void gemm_bf16_mfma(
    const unsigned short* __restrict__ A, const unsigned short* __restrict__ BT,
    const float* __restrict__ bias, void* __restrict__ Cout,
    int M, int N, int K,
    const float* __restrict__ loss_acc, float* __restrict__ loss_out) {
  constexpr int BM = 4 * WM;
  constexpr int MT = WM / 16;

  __shared__ unsigned short As[BM][40];
  __shared__ unsigned short Bs[64][40];

  const int tid  = threadIdx.x;
  const int wave = tid >> 6;
  const int lane = tid & 63;
  const int quad = lane >> 4;
  const int l16  = lane & 15;
  const int row0 = blockIdx.y * BM;
  const int col0 = blockIdx.x * 64;

  if (DO_LOSS && blockIdx.x == 0 && blockIdx.y == 0 && tid == 0)
    loss_out[0] = 0.5f * loss_acc[0] / (float)((size_t)NROWS * GD);

  f32x4 acc[MT][4];
#pragma unroll
  for (int mt = 0; mt < MT; ++mt)
#pragma unroll
    for (int nt = 0; nt < 4; ++nt) acc[mt][nt] = (f32x4){0.f, 0.f, 0.f, 0.f};

  for (int k0 = 0; k0 < K; k0 += 32) {
    __syncthreads();
    if constexpr (BM == 128) {
      const int r = tid >> 1, seg = (tid & 1) * 16;
      const uint4* src = reinterpret_cast<const uint4*>(
          &A[(size_t)(row0 + r) * K + k0 + seg]);
      uint4* dst = reinterpret_cast<uint4*>(&As[r][seg]);
      dst[0] = src[0]; dst[1] = src[1];
    } else {
      const int r = tid >> 2, seg = (tid & 3) * 8;
      *reinterpret_cast<uint4*>(&As[r][seg]) =
          *reinterpret_cast<const uint4*>(&A[(size_t)(row0 + r) * K + k0 + seg]);
    }
    {
      const int n = tid >> 2, kc = (tid & 3) * 8;
      *reinterpret_cast<uint4*>(&Bs[n][kc]) =
          *reinterpret_cast<const uint4*>(&BT[(size_t)(col0 + n) * K + k0 + kc]);
    }
    __syncthreads();

    bf16x8 af[MT], bf[4];
#pragma unroll
    for (int mt = 0; mt < MT; ++mt)
      af[mt] = *reinterpret_cast<const bf16x8*>(
          &As[wave * WM + mt * 16 + l16][quad * 8]);
#pragma unroll
    for (int nt = 0; nt < 4; ++nt)
      bf[nt] = *reinterpret_cast<const bf16x8*>(&Bs[nt * 16 + l16][quad * 8]);
#pragma unroll
    for (int mt = 0; mt < MT; ++mt)
#pragma unroll
      for (int nt = 0; nt < 4; ++nt)
        acc[mt][nt] = __builtin_amdgcn_mfma_f32_16x16x32_bf16(
            af[mt], bf[nt], acc[mt][nt], 0, 0, 0);
  }

#pragma unroll
  for (int mt = 0; mt < MT; ++mt)
#pragma unroll
    for (int nt = 0; nt < 4; ++nt) {
      const int col = col0 + nt * 16 + l16;
      const float bv = bias[col];
#pragma unroll
      for (int r = 0; r < 4; ++r) {
        const int grow = row0 + wave * WM + mt * 16 + quad * 4 + r;
        float v = acc[mt][nt][r] + bv;
        if constexpr (OUT_BF16) {
          v = fmaxf(v, 0.0f);
          ((unsigned short*)Cout)[(size_t)grow * N + col] = f2bf(v);
        } else {
          ((float*)Cout)[(size_t)grow * N + col] = v;
        }
      }
    }
}

// ---------------------------------------------------------------------------
// prep_cn: cn = -0.5*||codebook||^2 (MFMA-accumulator seed for argmax form)
// + zero loss accumulator.  Runs FIRST.
// ---------------------------------------------------------------------------
__global__ void prep_cn(const float* __restrict__ cb, float* __restrict__ cn,
                        float* __restrict__ loss_acc) {
  const int i = blockIdx.x * 256 + threadIdx.x;
  if (i == 0) loss_acc[0] = 0.0f;
  if (i < GQ * KQ) {
    const float* c = cb + (size_t)i * GD;
    float s = 0.0f;
#pragma unroll
    for (int d = 0; d < GD; ++d) s = fmaf(c[d], c[d], s);
    cn[i] = -0.5f * s;
  }
}

// ---------------------------------------------------------------------------
// prep_wT: decoder weights -> TRANSPOSED bf16 (w1bT, w2bT)
// + codebook -> swizzled VQ records for conflict-free LDS staging:
//   rec[(g*16+ch)*6272]: tier t in {h,m,l} at t*2048 + slot*8, where
//   slot = nt*64 + quad*16 + l16 encodes (code = ch*64+nt*16+l16, dims
//   quad*8..+8) -- the EXACT lane order vq_mfma's wave reads (lane-contiguous
//   16B on both ds_write and ds_read => zero bank conflicts).  cn[64] at 6144.
// MUST run after enc2 (all outputs overlay the then-dead fp32 H region).
// ---------------------------------------------------------------------------
__global__ void prep_wT(const float* __restrict__ w1, const float* __restrict__ w2,
                        const float* __restrict__ cbk, const float* __restrict__ cn,
                        unsigned short* __restrict__ w1bT,
                        unsigned short* __restrict__ w2bT,
                        unsigned short* __restrict__ rec) {
  const int t = blockIdx.x * 256 + threadIdx.x;
  if (t < 16384) {                       // w1: [256 k][512 n] -> w1bT[n][k]
    const int n = t >> 5, k0 = (t & 31) * 8;
    alignas(16) unsigned short o[8];
#pragma unroll
    for (int q = 0; q < 8; ++q) o[q] = f2bf(w1[(size_t)(k0 + q) * HIDDEN + n]);
    *reinterpret_cast<uint4*>(&w1bT[(size_t)n * LATENT + k0]) =
        *reinterpret_cast<const uint4*>(o);
  } else if (t < 20480) {                // w2: [512 k][64 n] -> w2bT[n][k]
    const int u = t - 16384;
    const int n = u >> 6, k0 = (u & 63) * 8;
    alignas(16) unsigned short o[8];
#pragma unroll
    for (int q = 0; q < 8; ++q) o[q] = f2bf(w2[(size_t)(k0 + q) * NBANDS + n]);
    *reinterpret_cast<uint4*>(&w2bT[(size_t)n * HIDDEN + k0]) =
        *reinterpret_cast<const uint4*>(o);
  } else if (t < 53248) {                // codebook split -> swizzled records
    const int e0 = (t - 20480) * 8;      // 8 consecutive dims of one code
    const int gidx = e0 >> 15;           // /(KQ*GD)
    const int w    = e0 & 32767;
    const int code = w >> 5;
    const int d0   = w & 31;             // 0,8,16,24
    const int quad = d0 >> 3;
    const int ch   = code >> 6;
    const int cw   = code & 63;
    const int nt   = cw >> 4;
    const int l16  = cw & 15;
    const int slot = nt * 64 + quad * 16 + l16;
    unsigned short* recb = rec + (size_t)(gidx * 16 + ch) * VQ_REC_SH;
    alignas(16) unsigned short oh[8], om[8], ol[8];
#pragma unroll
    for (int q = 0; q < 8; ++q) split3(cbk[e0 + q], oh[q], om[q], ol[q]);
    *reinterpret_cast<uint4*>(&recb[slot * 8]) =
        *reinterpret_cast<const uint4*>(oh);
    *reinterpret_cast<uint4*>(&recb[2048 + slot * 8]) =
        *reinterpret_cast<const uint4*>(om);
    *reinterpret_cast<uint4*>(&recb[4096 + slot * 8]) =
        *reinterpret_cast<const uint4*>(ol);
  } else if (t < 61440) {                // cn -> record tail
    const int i = t - 53248;             // 0..8191
    const int gidx = i >> 10, code = i & 1023;
    const int ch = code >> 6, cw = code & 63;
    unsigned short* recb = rec + (size_t)(gidx * 16 + ch) * VQ_REC_SH;
    *reinterpret_cast<float*>(&recb[6144 + cw * 2]) = cn[(size_t)gidx * KQ + code];
  }
}

// ---------------------------------------------------------------------------
// vq_mfma v6: VQ search on the MATRIX pipe, LDS-staged, conflict-free.
//
// cross via 3-way bf16 split (6 MFMAs/acc: hh,hm,mh,hl,mm,lh) -> fp32-class
// error; score = -0.5*||c||^2 + cross (seeded via C-in); argMAX score.
//
// Round-5 diagnosis: (a) VqStg structs held across barriers were demoted to
// SCRATCH (+120MB HBM writes); (b) 64B-stride fragment reads = 8-way bank
// conflict (3.07M).  v6 fixes both mechanically:
//  * staging in 4 plain locals (uint4 Lh,Lm,Ll; float Lc), assigned
//    unconditionally -- nothing for the compiler to demote;
//  * records pre-swizzled to LANE order by prep_wT: staging load, ds_write,
//    and compute ds_read_b128 are all lane-contiguous 16B -> 0 conflicts;
//  * one barrier per chunk; loads for c+2 issued after ds_write of c+1
//    (register renaming gives issue-early); barrier's vmcnt(0) drain is free
//    because the only outstanding loads were just consumed by the ds_write;
//  * __launch_bounds__(256,4): cap 128 VGPR (est. ~100 live) -> 4 waves/SIMD,
//    matching the grid's 15.6 waves/CU.
// Per-accumulator MFMA tier order and select order UNCHANGED -> bit-identical.
//
// Block: 256 thr = 4 waves x 32 rows = 128 rows; grid (125, 8 groups).
// LDS 2 x 6272 shorts = 25088 B.
// ---------------------------------------------------------------------------
__device__ __forceinline__ void vq_write(
    unsigned short (&buf)[VQ_REC_SH], int tid,
    const uint4& h, const uint4& m, const uint4& l, float c) {
  *reinterpret_cast<uint4*>(&buf[tid * 8])        = h;
  *reinterpret_cast<uint4*>(&buf[2048 + tid * 8]) = m;
  *reinterpret_cast<uint4*>(&buf[4096 + tid * 8]) = l;
  if (tid < 64) *reinterpret_cast<float*>(&buf[6144 + tid * 2]) = c;
}

// One nt-PAIR: 12 MFMAs across 4 accumulators (per-acc tier order:
// ah*h, ah*m, am*h, ah*l, am*m, al*h -- identical to rounds 1/3/4/5).
__device__ __forceinline__ void vq_pair(
    const bf16x8 (&ah)[2], const bf16x8 (&am)[2], const bf16x8 (&al)[2],
    const unsigned short (&buf)[VQ_REC_SH], int lane, int l16, int nt0, int ch,
    float (&best)[8], int (&bidx)[8]) {
  bf16x8 Fh[2], Fm[2], Fl[2];
  float  Fc[2];
#pragma unroll
  for (int p = 0; p < 2; ++p) {
    const int off = ((nt0 + p) * 64 + lane) * 8;        // lane-contiguous 16B
    Fh[p] = *reinterpret_cast<const bf16x8*>(&buf[off]);
    Fm[p] = *reinterpret_cast<const bf16x8*>(&buf[2048 + off]);
    Fl[p] = *reinterpret_cast<const bf16x8*>(&buf[4096 + off]);
    Fc[p] = *reinterpret_cast<const float*>(&buf[6144 + (((nt0 + p) * 16 + l16) << 1)]);
  }
  f32x4 a00 = {Fc[0], Fc[0], Fc[0], Fc[0]};
  f32x4 a01 = a00;
  f32x4 a10 = {Fc[1], Fc[1], Fc[1], Fc[1]};
  f32x4 a11 = a10;
  a00 = __builtin_amdgcn_mfma_f32_16x16x32_bf16(ah[0], Fh[0], a00, 0, 0, 0);
  a01 = __builtin_amdgcn_mfma_f32_16x16x32_bf16(ah[1], Fh[0], a01, 0, 0, 0);
  a10 = __builtin_amdgcn_mfma_f32_16x16x32_bf16(ah[0], Fh[1], a10, 0, 0, 0);
  a11 = __builtin_amdgcn_mfma_f32_16x16x32_bf16(ah[1], Fh[1], a11, 0, 0, 0);
  a00 = __builtin_amdgcn_mfma_f32_16x16x32_bf16(ah[0], Fm[0], a00, 0, 0, 0);
  a01 = __builtin_amdgcn_mfma_f32_16x16x32_bf16(ah[1], Fm[0], a01, 0, 0, 0);
  a10 = __builtin_amdgcn_mfma_f32_16x16x32_bf16(ah[0], Fm[1], a10, 0, 0, 0);
  a11 = __builtin_amdgcn_mfma_f32_16x16x32_bf16(ah[1], Fm[1], a11, 0, 0, 0);
  a00 = __builtin_amdgcn_mfma_f32_16x16x32_bf16(am[0], Fh[0], a00, 0, 0, 0);
  a01 = __builtin_amdgcn_mfma_f32_16x16x32_bf16(am[1], Fh[0], a01, 0, 0, 0);
  a10 = __builtin_amdgcn_mfma_f32_16x16x32_bf16(am[0], Fh[1], a10, 0, 0, 0);
  a11 = __builtin_amdgcn_mfma_f32_16x16x32_bf16(am[1], Fh[1], a11, 0, 0, 0);
  a00 = __builtin_amdgcn_mfma_f32_16x16x32_bf16(ah[0], Fl[0], a00, 0, 0, 0);
  a01 = __builtin_amdgcn_mfma_f32_16x16x32_bf16(ah[1], Fl[0], a01, 0, 0, 0);
  a10 = __builtin_amdgcn_mfma_f32_16x16x32_bf16(ah[0], Fl[1], a10, 0, 0, 0);
  a11 = __builtin_amdgcn_mfma_f32_16x16x32_bf16(ah[1], Fl[1], a11, 0, 0, 0);
  a00 = __builtin_amdgcn_mfma_f32_16x16x32_bf16(am[0], Fm[0], a00, 0, 0, 0);
  a01 = __builtin_amdgcn_mfma_f32_16x16x32_bf16(am[1], Fm[0], a01, 0, 0, 0);
  a10 = __builtin_amdgcn_mfma_f32_16x16x32_bf16(am[0], Fm[1], a10, 0, 0, 0);
  a11 = __builtin_amdgcn_mfma_f32_16x16x32_bf16(am[1], Fm[1], a11, 0, 0, 0);
  a00 = __builtin_amdgcn_mfma_f32_16x16x32_bf16(al[0], Fh[0], a00, 0, 0, 0);
  a01 = __builtin_amdgcn_mfma_f32_16x16x32_bf16(al[1], Fh[0], a01, 0, 0, 0);
  a10 = __builtin_amdgcn_mfma_f32_16x16x32_bf16(al[0], Fh[1], a10, 0, 0, 0);
  a11 = __builtin_amdgcn_mfma_f32_16x16x32_bf16(al[1], Fh[1], a11, 0, 0, 0);
  // selects in ascending-nt order (same global compare order as before)
  {
    const int code = ch * 64 + nt0 * 16 + l16;
#pragma unroll
    for (int r = 0; r < 4; ++r) {
      if (a00[r] > best[r])     { best[r]     = a00[r]; bidx[r]     = code; }
      if (a01[r] > best[4 + r]) { best[4 + r] = a01[r]; bidx[4 + r] = code; }
    }
  }
  {
    const int code = ch * 64 + (nt0 + 1) * 16 + l16;
#pragma unroll
    for (int r = 0; r < 4; ++r) {
      if (a10[r] > best[r])     { best[r]     = a10[r]; bidx[r]     = code; }
      if (a11[r] > best[4 + r]) { best[4 + r] = a11[r]; bidx[4 + r] = code; }
    }
  }
}

__global__ __launch_bounds__(256, 4) void vq_mfma(
    const float* __restrict__ z_e, const float* __restrict__ cb,
    const unsigned short* __restrict__ rec,
    float* __restrict__ z_q, unsigned short* __restrict__ zqb,
    float* __restrict__ idx_out, float* __restrict__ loss_acc) {
  __shared__ __align__(16) unsigned short lds0[VQ_REC_SH];
  __shared__ __align__(16) unsigned short lds1[VQ_REC_SH];

  const int g    = blockIdx.y;
  const int row0 = blockIdx.x * 128;
  const int tid  = threadIdx.x;
  const int wave = tid >> 6;
  const int lane = tid & 63;
  const int quad = lane >> 4;
  const int l16  = lane & 15;

  const unsigned short* recg = rec + (size_t)g * 16 * VQ_REC_SH;
  const size_t cb0 = (size_t)g * KQ * GD;

  // staging registers: plain locals, unconditional assignment (no scratch)
  uint4 Lh, Lm, Ll; float Lc;
#define VQ_LDG(chk) do {                                                    \
    const unsigned short* _b = recg + (chk) * VQ_REC_SH;                    \
    Lh = *reinterpret_cast<const uint4*>(&_b[tid * 8]);                     \
    Lm = *reinterpret_cast<const uint4*>(&_b[2048 + tid * 8]);              \
    Ll = *reinterpret_cast<const uint4*>(&_b[4096 + tid * 8]);              \
    Lc = *reinterpret_cast<const float*>(&_b[6144 + tid * 2]);              \
  } while (0)

  VQ_LDG(0);                              // chunk 0 in flight

  // ---- A fragments: rows wave*32 + mt*16 + l16, dims quad*8..+8 (in-reg split)
  bf16x8 ah[2], am[2], al[2];
#pragma unroll
  for (int mt = 0; mt < 2; ++mt) {
    const float* zp = &z_e[(size_t)(row0 + wave * 32 + mt * 16 + l16) * LATENT
                           + g * GD + quad * 8];
    const float4 x0 = *reinterpret_cast<const float4*>(zp);
    const float4 x1 = *reinterpret_cast<const float4*>(zp + 4);
    const float xv[8] = {x0.x, x0.y, x0.z, x0.w, x1.x, x1.y, x1.z, x1.w};
    bf16x8 vh, vm, vl;
#pragma unroll
    for (int j = 0; j < 8; ++j) {
      unsigned short sh, sm, sl;
      split3(xv[j], sh, sm, sl);
      vh[j] = (short)sh; vm[j] = (short)sm; vl[j] = (short)sl;
    }
    ah[mt] = vh; am[mt] = vm; al[mt] = vl;
  }

  float best[8];
  int   bidx[8];
#pragma unroll
  for (int i = 0; i < 8; ++i) { best[i] = -3.0e38f; bidx[i] = 0; }

  // ---- prologue: write chunk 0, start loads for chunk 1
  vq_write(lds0, tid, Lh, Lm, Ll, Lc);
  VQ_LDG(1);
  __syncthreads();

  // ---- main loop: 2 chunks / iteration, ONE barrier per chunk
#pragma unroll 1
  for (int cp = 0; cp < 8; ++cp) {
    const int c = 2 * cp;
    vq_pair(ah, am, al, lds0, lane, l16, 0, c, best, bidx);
    vq_pair(ah, am, al, lds0, lane, l16, 2, c, best, bidx);
    vq_write(lds1, tid, Lh, Lm, Ll, Lc);           // chunk c+1
    if (c + 2 < 16) VQ_LDG(c + 2);
    __syncthreads();

    vq_pair(ah, am, al, lds1, lane, l16, 0, c + 1, best, bidx);
    vq_pair(ah, am, al, lds1, lane, l16, 2, c + 1, best, bidx);
    if (c + 2 < 16) {
      vq_write(lds0, tid, Lh, Lm, Ll, Lc);         // chunk c+2
      if (c + 3 < 16) VQ_LDG(c + 3);
      __syncthreads();
    }
  }
#undef VQ_LDG

  // ---- per-row reduce across the 16 l16-lanes (codes == l16 mod 16), then
  // 16 lanes cooperate on the 32-dim epilogue (2 dims each).
  float sse_local = 0.0f;
#pragma unroll
  for (int s8 = 0; s8 < 8; ++s8) {
    float mb = best[s8];
    int   mi = bidx[s8];
#pragma unroll
    for (int m = 1; m < 16; m <<= 1) {
      const float ov = __shfl_xor(mb, m, 64);
      const int   oi = __shfl_xor(mi, m, 64);
      if (ov > mb || (ov == mb && oi < mi)) { mb = ov; mi = oi; }
    }
    // all 16 lanes of this quad-group now agree on (mb, mi)
    const int mt  = s8 >> 2;
    const int r   = s8 & 3;
    const int row = row0 + wave * 32 + mt * 16 + quad * 4 + r;
    const float2 cw = *reinterpret_cast<const float2*>(
        &cb[cb0 + (size_t)mi * GD + 2 * l16]);
    const float2 zv = *reinterpret_cast<const float2*>(
        &z_e[(size_t)row * LATENT + g * GD + 2 * l16]);
    const float d0 = cw.x - zv.x;
    const float d1 = cw.y - zv.y;
    sse_local = fmaf(d0, d0, fmaf(d1, d1, sse_local));
    *reinterpret_cast<float2*>(
        &z_q[(size_t)row * LATENT + g * GD + 2 * l16]) = cw;
    const unsigned pz = (unsigned)f2bf(cw.x) | ((unsigned)f2bf(cw.y) << 16);
    *reinterpret_cast<unsigned*>(
        &zqb[(size_t)row * LATENT + g * GD + 2 * l16]) = pz;
    if (l16 == 0) idx_out[(size_t)row * GQ + g] = (float)mi;
  }

#pragma unroll
  for (int m = 1; m < 64; m <<= 1) sse_local += __shfl_xor(sse_local, m, 64);
  if (lane == 0) atomicAdd(loss_acc, sse_local);
}

// ---------------------------------------------------------------------------
extern "C" void kernel_launch(void* const* d_in, const int* in_sizes, int n_in,
                              void* d_out, int out_size, void* d_ws, size_t ws_size,
                              hipStream_t stream) {
  const float* bands  = (const float*)d_in[0];
  const float* enc_w1 = (const float*)d_in[1];
  const float* enc_b1 = (const float*)d_in[2];
  const float* enc_w2 = (const float*)d_in[3];
  const float* enc_b2 = (const float*)d_in[4];
  const float* cbooks = (const float*)d_in[5];
  const float* dec_w1 = (const float*)d_in[6];
  const float* dec_b1 = (const float*)d_in[7];
  const float* dec_w2 = (const float*)d_in[8];
  const float* dec_b2 = (const float*)d_in[9];

  float* out = (float*)d_out;
  float* ws  = (float*)d_ws;

  float* bands_hat = out + OUT_BH;
  float* z_e       = out + OUT_ZE;
  float* z_q       = out + OUT_ZQ;
  float* idx_f     = out + OUT_IDX;
  float* loss_out  = out + OUT_LOSS;

  float* H        = ws + WS_H;
  float* cn       = ws + WS_CN;
  float* loss_acc = ws + WS_LOSS;
  unsigned short* h2bf = (unsigned short*)(ws + WS_H2BF_F);
  unsigned short* zqb  = (unsigned short*)(ws + WS_ZQB_F);
  unsigned short* w1bT = (unsigned short*)(ws + WS_W1B_F);
  unsigned short* w2bT = (unsigned short*)(ws + WS_W2B_F);
  unsigned short* rec  = (unsigned short*)(ws + WS_REC_F);

  // cn (= -0.5||c||^2) + loss zero (safe: outside H region)
  prep_cn<<<dim3(32), dim3(256), 0, stream>>>(cbooks, cn, loss_acc);

  // Encoder (fp32): H = relu(bands@W1+b1); z_e = H@W2+b2 (enc2 BK=32)
  gemm_f32<128, 8, 8, 16, true ><<<dim3(HIDDEN / 128, NROWS / 128), dim3(256), 0, stream>>>(
      bands, enc_w1, enc_b1, H, NROWS, HIDDEN, NBANDS);
  gemm_f32<64, 4, 8, 32, false><<<dim3(LATENT / 64, NROWS / 128), dim3(256), 0, stream>>>(
      H, enc_w2, enc_b2, z_e, NROWS, LATENT, HIDDEN);

  // Decoder weights -> transposed bf16; codebook -> swizzled VQ records
  // (H is dead now; overlays are safe)
  prep_wT<<<dim3(240), dim3(256), 0, stream>>>(
      dec_w1, dec_w2, cbooks, cn, w1bT, w2bT, rec);

  // VQ on the matrix pipe (fp32-class accuracy via 6-MFMA split), LDS-staged
  vq_mfma<<<dim3(NROWS / 128, GQ), dim3(256), 0, stream>>>(
      z_e, cbooks, rec, z_q, zqb, idx_f, loss_acc);

  // Decoder (bf16 MFMA, transposed-weight staging); dec1 finalizes loss
  gemm_bf16_mfma<32, true, true ><<<dim3(HIDDEN / 64, NROWS / 128), dim3(256), 0, stream>>>(
      zqb, w1bT, dec_b1, (void*)h2bf, NROWS, HIDDEN, LATENT, loss_acc, loss_out);
  gemm_bf16_mfma<16, false, false><<<dim3(NBANDS / 64, NROWS / 64), dim3(256), 0, stream>>>(
      h2bf, w2bT, dec_b2, (void*)bands_hat, NROWS, NBANDS, HIDDEN, loss_acc, loss_out);
}